// Round 5
// baseline (32.693 us; speedup 1.0000x reference)
//
#include <hip/hip_runtime.h>

// ---------------- problem constants ----------------
#define DTSTEP  3600.0
#define T_STEPS 1048576
#define LCH     16                    // u-rows per chunk (one chunk per thread)
#define NCH     (T_STEPS/LCH)         // 65536 chunks
#define SUP     64                    // chunks per superchunk (one LDS segment)
#define NSUP    (NCH/SUP)             // 1024 superchunks

// ---------------- workspace layout (float offsets) ----------------
#define OFF_M    0                    // M = I + DT*A                    (9)
#define OFF_N    9                    // N = DT*B                        (15)
#define OFF_PP   24                   // P^(2^r), P = M^16,   r=0..5     (54)
#define OFF_QP   78                   // Q^(2^r), Q = M^1024, r=0..9     (90)
#define OFF_FLAG 200                  // 1.0 if inputs are bf16, 0.0 if f32
#define OFF_W    256                  // superchunk aggregates           (NSUP*3)
#define OFF_S    (OFF_W + NSUP*3)     // superchunk start states         (NSUP*3)
// total ws use: (OFF_S + NSUP*3)*4 = 25,600 bytes

__device__ inline float bf16up(unsigned short h){
  return __uint_as_float(((unsigned int)h) << 16);
}

__device__ inline void matsq3(double* C){
  double R[9];
#pragma unroll
  for (int r=0;r<3;r++){
#pragma unroll
    for (int c=0;c<3;c++){
      R[r*3+c] = C[r*3+0]*C[0+c] + C[r*3+1]*C[3+c] + C[r*3+2]*C[6+c];
    }
  }
#pragma unroll
  for (int k=0;k<9;k++) C[k]=R[k];
}

// one thread: sniff input dtype, build M,N (f32) and matrix powers via f64 squaring
__global__ void k_setup(const void* __restrict__ rc_p, const void* __restrict__ u_p,
                        float* __restrict__ ws){
  if (threadIdx.x != 0 || blockIdx.x != 0) return;
  // ---- dtype sniff: decode first 32 halfwords of u as bf16 ----
  const unsigned short* up = (const unsigned short*)u_p;
  int cnt = 0;
  for (int k=0;k<32;k++){
    const float a = fabsf(bf16up(up[k]));
    if (!(a > 1e-4f && a < 100.0f)) cnt++;
  }
  const int isb = (cnt < 8);
  ws[OFF_FLAG] = isb ? 1.0f : 0.0f;
  float rcv[7];
  if (isb){
    const unsigned short* rp = (const unsigned short*)rc_p;
    for (int k=0;k<7;k++) rcv[k] = bf16up(rp[k]);
  } else {
    const float* rp = (const float*)rc_p;
    for (int k=0;k<7;k++) rcv[k] = rp[k];
  }
  const float Rg = rcv[0]*10.f+1.f, Ri = rcv[1]*10.f+1.f, Re = rcv[2]*10.f+1.f, Rw = rcv[3]*10.f+1.f;
  const float Cai = rcv[4]*1e6f+1e5f, Cwe = rcv[5]*1e6f+1e5f, Cwi = rcv[6]*1e6f+1e5f;
  double A[9];
  A[0] = -(1.0/Rg + 1.0/Ri)/Cai;          A[1] = 0.0;                              A[2] = 1.0/((double)Ri*(double)Cai);
  A[3] = 0.0;                              A[4] = -(1.0/Re + 1.0/Rw)/Cwe;          A[5] = 1.0/((double)Rw*(double)Cwe);
  A[6] = 1.0/((double)Ri*(double)Cwi);     A[7] = 1.0/((double)Rw*(double)Cwi);    A[8] = -(1.0/Rw + 1.0/Ri)/Cwi;
  double Bm[15] = {
    1.0/((double)Rg*(double)Cai), 1.0/(double)Cai, 1.0/(double)Cai, 0.0, 0.0,
    1.0/((double)Re*(double)Cwe), 0.0, 0.0, 1.0/(double)Cwe, 0.0,
    0.0, 0.0, 0.0, 0.0, 1.0/(double)Cwi };
  double Md[9];
#pragma unroll
  for (int k=0;k<9;k++) Md[k] = DTSTEP*A[k];
  Md[0]+=1.0; Md[4]+=1.0; Md[8]+=1.0;
#pragma unroll
  for (int k=0;k<9;k++)  ws[OFF_M+k] = (float)Md[k];
#pragma unroll
  for (int k=0;k<15;k++) ws[OFF_N+k] = (float)(DTSTEP*Bm[k]);
  double C[9];
#pragma unroll
  for (int k=0;k<9;k++) C[k]=Md[k];
  matsq3(C); matsq3(C); matsq3(C); matsq3(C);            // M^16 = P
  for (int r=0;r<6;r++){
    if (r) matsq3(C);                                    // P^(2^r)
    for (int k=0;k<9;k++) ws[OFF_PP + r*9 + k] = (float)C[k];
  }
  matsq3(C);                                             // P^64 = M^1024 = Q
  for (int r=0;r<10;r++){
    if (r) matsq3(C);                                    // Q^(2^r)
    for (int k=0;k<9;k++) ws[OFF_QP + r*9 + k] = (float)C[k];
  }
}

struct MN { float M0,M2,M4,M5,M6,M7,M8, N0,N1,N2,N5,N8,N14; };

__device__ inline MN load_mn(const float* __restrict__ ws){
  MN p;
  p.M0=ws[OFF_M+0]; p.M2=ws[OFF_M+2]; p.M4=ws[OFF_M+4]; p.M5=ws[OFF_M+5];
  p.M6=ws[OFF_M+6]; p.M7=ws[OFF_M+7]; p.M8=ws[OFF_M+8];
  p.N0=ws[OFF_N+0]; p.N1=ws[OFF_N+1]; p.N2=ws[OFF_N+2];
  p.N5=ws[OFF_N+5]; p.N8=ws[OFF_N+8]; p.N14=ws[OFF_N+14];
  return p;
}

// dtype-adaptive load of this chunk's 80 u values (16B-aligned vector loads both ways)
__device__ inline void load_u(const void* __restrict__ u_p, int i, int isb, float* uu){
  if (isb){
    const uint4* p = reinterpret_cast<const uint4*>((const unsigned short*)u_p + (size_t)i*(LCH*5));
#pragma unroll
    for (int k=0;k<LCH*5/8;k++){
      const uint4 q = p[k];
      const unsigned int w[4] = {q.x,q.y,q.z,q.w};
#pragma unroll
      for (int m=0;m<4;m++){
        uu[k*8+2*m+0] = __uint_as_float((w[m] & 0xFFFFu) << 16);
        uu[k*8+2*m+1] = __uint_as_float(w[m] & 0xFFFF0000u);
      }
    }
  } else {
    const float4* u4 = reinterpret_cast<const float4*>((const float*)u_p) + (size_t)i*(LCH*5/4);
#pragma unroll
    for (int k=0;k<LCH*5/4;k++){
      const float4 q = u4[k];
      uu[k*4+0]=q.x; uu[k*4+1]=q.y; uu[k*4+2]=q.z; uu[k*4+3]=q.w;
    }
  }
}

// v = sum_j M^(LCH-1-j) * (N u_j)   via   v <- M v + N u_j
__device__ inline void chunk_v(const float* uu, const MN& mn, float& v0, float& v1, float& v2){
  v0=0.f; v1=0.f; v2=0.f;
#pragma unroll
  for (int j=0;j<LCH;j++){
    const float u0=uu[j*5+0],u1=uu[j*5+1],u2=uu[j*5+2],u3=uu[j*5+3],u4v=uu[j*5+4];
    const float c0 = fmaf(mn.N0,u0, fmaf(mn.N1,u1, mn.N2*u2));
    const float c1 = fmaf(mn.N5,u0, mn.N8*u3);
    const float c2 = mn.N14*u4v;
    const float n0 = fmaf(mn.M0,v0, fmaf(mn.M2,v2, c0));
    const float n1 = fmaf(mn.M4,v1, fmaf(mn.M5,v2, c1));
    const float n2 = fmaf(mn.M6,v0, fmaf(mn.M7,v1, fmaf(mn.M8,v2, c2)));
    v0=n0; v1=n1; v2=n2;
  }
}

// K1: per-chunk v from u, LDS segmented affine scan (64-wide) -> superchunk aggregate w
__global__ __launch_bounds__(256) void k_agg(const void* __restrict__ u,
                                             float* __restrict__ ws){
  __shared__ float buf[2][256*3];
  const int tid  = threadIdx.x;
  const int i    = blockIdx.x*256 + tid;               // chunk id
  const int lane = tid & 63;                           // position within superchunk
  const int isb  = (ws[OFF_FLAG] != 0.0f);
  float uu[LCH*5];
  load_u(u, i, isb, uu);
  const MN mn = load_mn(ws);
  float t0,t1,t2;
  chunk_v(uu, mn, t0,t1,t2);
  buf[0][tid*3+0]=t0; buf[0][tid*3+1]=t1; buf[0][tid*3+2]=t2;
  __syncthreads();
  int cur=0;
#pragma unroll
  for (int r=0;r<6;r++){
    const int d = 1<<r;
    const float Q0=ws[OFF_PP+r*9+0],Q1=ws[OFF_PP+r*9+1],Q2=ws[OFF_PP+r*9+2],
                Q3=ws[OFF_PP+r*9+3],Q4=ws[OFF_PP+r*9+4],Q5=ws[OFF_PP+r*9+5],
                Q6=ws[OFF_PP+r*9+6],Q7=ws[OFF_PP+r*9+7],Q8=ws[OFF_PP+r*9+8];
    float p0=0.f,p1=0.f,p2=0.f;
    if (lane >= d){
      const int s=(tid-d)*3;
      p0=buf[cur][s+0]; p1=buf[cur][s+1]; p2=buf[cur][s+2];
    }
    t0 = fmaf(Q0,p0, fmaf(Q1,p1, fmaf(Q2,p2, t0)));
    t1 = fmaf(Q3,p0, fmaf(Q4,p1, fmaf(Q5,p2, t1)));
    t2 = fmaf(Q6,p0, fmaf(Q7,p1, fmaf(Q8,p2, t2)));
    buf[cur^1][tid*3+0]=t0; buf[cur^1][tid*3+1]=t1; buf[cur^1][tid*3+2]=t2;
    __syncthreads();
    cur ^= 1;
  }
  if (lane==63){
    const int sc = i>>6;
    ws[OFF_W+sc*3+0]=t0; ws[OFF_W+sc*3+1]=t1; ws[OFF_W+sc*3+2]=t2;
  }
}

// K3: single-block LDS scan over 1024 superchunk aggregates (x_init folded into element 0)
__global__ __launch_bounds__(1024) void k_scan(const void* __restrict__ x_init_p,
                                               float* __restrict__ ws){
  __shared__ float buf[2][NSUP*3];
  const int t = threadIdx.x;
  float i0=ws[OFF_W+t*3+0], i1=ws[OFF_W+t*3+1], i2=ws[OFF_W+t*3+2];
  float xi0,xi1,xi2;
  if (ws[OFF_FLAG] != 0.0f){
    const unsigned short* xp = (const unsigned short*)x_init_p;
    xi0=bf16up(xp[0]); xi1=bf16up(xp[1]); xi2=bf16up(xp[2]);
  } else {
    const float* xp = (const float*)x_init_p;
    xi0=xp[0]; xi1=xp[1]; xi2=xp[2];
  }
  if (t==0){
    const float Q0=ws[OFF_QP+0],Q1=ws[OFF_QP+1],Q2=ws[OFF_QP+2],
                Q3=ws[OFF_QP+3],Q4=ws[OFF_QP+4],Q5=ws[OFF_QP+5],
                Q6=ws[OFF_QP+6],Q7=ws[OFF_QP+7],Q8=ws[OFF_QP+8];
    i0 = fmaf(Q0,xi0, fmaf(Q1,xi1, fmaf(Q2,xi2, i0)));
    i1 = fmaf(Q3,xi0, fmaf(Q4,xi1, fmaf(Q5,xi2, i1)));
    i2 = fmaf(Q6,xi0, fmaf(Q7,xi1, fmaf(Q8,xi2, i2)));
  }
  buf[0][t*3+0]=i0; buf[0][t*3+1]=i1; buf[0][t*3+2]=i2;
  __syncthreads();
  int cur=0;
#pragma unroll
  for (int r=0;r<10;r++){
    const int d = 1<<r;
    const float Q0=ws[OFF_QP+r*9+0],Q1=ws[OFF_QP+r*9+1],Q2=ws[OFF_QP+r*9+2],
                Q3=ws[OFF_QP+r*9+3],Q4=ws[OFF_QP+r*9+4],Q5=ws[OFF_QP+r*9+5],
                Q6=ws[OFF_QP+r*9+6],Q7=ws[OFF_QP+r*9+7],Q8=ws[OFF_QP+r*9+8];
    float p0=0.f,p1=0.f,p2=0.f;
    if (t >= d){
      const int s=(t-d)*3;
      p0=buf[cur][s+0]; p1=buf[cur][s+1]; p2=buf[cur][s+2];
    }
    i0 = fmaf(Q0,p0, fmaf(Q1,p1, fmaf(Q2,p2, i0)));
    i1 = fmaf(Q3,p0, fmaf(Q4,p1, fmaf(Q5,p2, i1)));
    i2 = fmaf(Q6,p0, fmaf(Q7,p1, fmaf(Q8,p2, i2)));
    buf[cur^1][t*3+0]=i0; buf[cur^1][t*3+1]=i1; buf[cur^1][t*3+2]=i2;
    __syncthreads();
    cur ^= 1;
  }
  if (t==0){ ws[OFF_S+0]=xi0; ws[OFF_S+1]=xi1; ws[OFF_S+2]=xi2; }
  if (t < NSUP-1){
    ws[OFF_S+(t+1)*3+0]=i0; ws[OFF_S+(t+1)*3+1]=i1; ws[OFF_S+(t+1)*3+2]=i2;
  }
}

// K4: recompute per-chunk v, LDS segmented scan -> exact chunk start states, replay,
// write FLOAT32 outputs (reference output dtype) via coalesced float4 stores
__global__ __launch_bounds__(256) void k_expand(const void* __restrict__ u,
                                                float* __restrict__ ws,
                                                float* __restrict__ out){
  __shared__ float buf[2][256*3];
  const int tid  = threadIdx.x;
  const int i    = blockIdx.x*256 + tid;             // chunk id
  const int lane = tid & 63;
  const int sc   = i >> 6;
  const int isb  = (ws[OFF_FLAG] != 0.0f);
  float uu[LCH*5];
  load_u(u, i, isb, uu);
  const MN mn = load_mn(ws);
  float t0,t1,t2;
  chunk_v(uu, mn, t0,t1,t2);
  const float s0=ws[OFF_S+sc*3+0], s1=ws[OFF_S+sc*3+1], s2=ws[OFF_S+sc*3+2];
  if (lane==0){
    const float P0=ws[OFF_PP+0],P1=ws[OFF_PP+1],P2=ws[OFF_PP+2],
                P3=ws[OFF_PP+3],P4=ws[OFF_PP+4],P5=ws[OFF_PP+5],
                P6=ws[OFF_PP+6],P7=ws[OFF_PP+7],P8=ws[OFF_PP+8];
    const float a0 = fmaf(P0,s0, fmaf(P1,s1, fmaf(P2,s2, t0)));
    const float a1 = fmaf(P3,s0, fmaf(P4,s1, fmaf(P5,s2, t1)));
    const float a2 = fmaf(P6,s0, fmaf(P7,s1, fmaf(P8,s2, t2)));
    t0=a0; t1=a1; t2=a2;
  }
  buf[0][tid*3+0]=t0; buf[0][tid*3+1]=t1; buf[0][tid*3+2]=t2;
  __syncthreads();
  int cur=0;
#pragma unroll
  for (int r=0;r<6;r++){
    const int d = 1<<r;
    const float Q0=ws[OFF_PP+r*9+0],Q1=ws[OFF_PP+r*9+1],Q2=ws[OFF_PP+r*9+2],
                Q3=ws[OFF_PP+r*9+3],Q4=ws[OFF_PP+r*9+4],Q5=ws[OFF_PP+r*9+5],
                Q6=ws[OFF_PP+r*9+6],Q7=ws[OFF_PP+r*9+7],Q8=ws[OFF_PP+r*9+8];
    float p0=0.f,p1=0.f,p2=0.f;
    if (lane >= d){
      const int s=(tid-d)*3;
      p0=buf[cur][s+0]; p1=buf[cur][s+1]; p2=buf[cur][s+2];
    }
    t0 = fmaf(Q0,p0, fmaf(Q1,p1, fmaf(Q2,p2, t0)));
    t1 = fmaf(Q3,p0, fmaf(Q4,p1, fmaf(Q5,p2, t1)));
    t2 = fmaf(Q6,p0, fmaf(Q7,p1, fmaf(Q8,p2, t2)));
    buf[cur^1][tid*3+0]=t0; buf[cur^1][tid*3+1]=t1; buf[cur^1][tid*3+2]=t2;
    __syncthreads();
    cur ^= 1;
  }
  // chunk start state = scan value of previous lane (segment-exclusive), lane 0 -> s
  float x0,x1,x2;
  if (lane==0){ x0=s0; x1=s1; x2=s2; }
  else { const int s=(tid-1)*3; x0=buf[cur][s+0]; x1=buf[cur][s+1]; x2=buf[cur][s+2]; }

  // xsol: f32 [T,3], chunk i covers flat [i*48, i*48+48); ysol: f32 [T] at base 3T
  float4* xo4 = reinterpret_cast<float4*>(out) + (size_t)i*12;
  float4* yo4 = reinterpret_cast<float4*>(out) + (size_t)(3*T_STEPS/4) + (size_t)i*4;
#pragma unroll
  for (int h=0; h<2; h++){
    float px[24]; float py[8];
#pragma unroll
    for (int j8=0;j8<8;j8++){
      const int j = h*8 + j8;
      py[j8]=x0;                                       // y_t = C x_t (pre-update)
      const float u0=uu[j*5+0],u1=uu[j*5+1],u2=uu[j*5+2],u3=uu[j*5+3],u4v=uu[j*5+4];
      const float c0 = fmaf(mn.N0,u0, fmaf(mn.N1,u1, mn.N2*u2));
      const float c1 = fmaf(mn.N5,u0, mn.N8*u3);
      const float c2 = mn.N14*u4v;
      const float n0 = fmaf(mn.M0,x0, fmaf(mn.M2,x2, c0));
      const float n1 = fmaf(mn.M4,x1, fmaf(mn.M5,x2, c1));
      const float n2 = fmaf(mn.M6,x0, fmaf(mn.M7,x1, fmaf(mn.M8,x2, c2)));
      x0=n0; x1=n1; x2=n2;
      px[j8*3+0]=x0; px[j8*3+1]=x1; px[j8*3+2]=x2;     // xsol_t = x_{t+1}
    }
#pragma unroll
    for (int m=0;m<6;m++)
      xo4[h*6+m] = make_float4(px[4*m+0],px[4*m+1],px[4*m+2],px[4*m+3]);
#pragma unroll
    for (int m=0;m<2;m++)
      yo4[h*2+m] = make_float4(py[4*m+0],py[4*m+1],py[4*m+2],py[4*m+3]);
  }
}

extern "C" void kernel_launch(void* const* d_in, const int* in_sizes, int n_in,
                              void* d_out, int out_size, void* d_ws, size_t ws_size,
                              hipStream_t stream) {
  (void)out_size; (void)ws_size;
  // robust input identification by element count (3 / T*5 / 7)
  const void* x_init = d_in[0];
  const void* u      = d_in[1];
  const void* rc     = d_in[2];
  for (int k=0;k<n_in;k++){
    if (in_sizes[k]==3) x_init = d_in[k];
    else if (in_sizes[k]==7) rc = d_in[k];
    else if (in_sizes[k]==T_STEPS*5) u = d_in[k];
  }
  float* ws = (float*)d_ws;                 // uses 25.6 KB
  float* out = (float*)d_out;               // f32 outputs (reference dtype)

  k_setup <<<1, 64, 0, stream>>>(rc, u, ws);
  k_agg   <<<NCH/256, 256, 0, stream>>>(u, ws);
  k_scan  <<<1, NSUP, 0, stream>>>(x_init, ws);
  k_expand<<<NCH/256, 256, 0, stream>>>(u, ws, out);
}

// Round 6
// 27.791 us; speedup vs baseline: 1.1764x; 1.1764x over previous
//
#include <hip/hip_runtime.h>

// ---------------- problem constants ----------------
#define DTSTEP  3600.0
#define T_STEPS 1048576
#define LCH     8                     // u-rows per chunk (one chunk per thread)
#define TPB     512                   // threads per block
#define NBLK    256                   // = T_STEPS/(TPB*LCH); block = 4096 steps
#define NAGG    NBLK                  // block aggregates

// ws: only the 256 block aggregates (3 floats each) = 3 KB
// Powers: sPW[k-3] = M^(2^k) as f32, k=3..19  (17 matrices)
//   intra-block scan round r (d=2^r chunks of 8 steps): PW[r],   r=0..8
//   aggregate  scan round r (d=2^r blocks of 4096):     PW[9+r], r=0..7
//   chunk transition P = M^8 = PW[0]; block transition R = M^4096 = PW[9]

__device__ inline void matsq3(double* C){
  double R[9];
#pragma unroll
  for (int r=0;r<3;r++){
#pragma unroll
    for (int c=0;c<3;c++){
      R[r*3+c] = C[r*3+0]*C[0+c] + C[r*3+1]*C[3+c] + C[r*3+2]*C[6+c];
    }
  }
#pragma unroll
  for (int k=0;k<9;k++) C[k]=R[k];
}

// thread-0-per-block setup: build M,N (f32) + 17 matrix powers via f64 squaring.
// sMN[13] = {M0,M2,M4,M5,M6,M7,M8, N0,N1,N2,N5,N8,N14}; sPW[17*9].
__device__ void setup_from_rc(const float* __restrict__ rc,
                              float* __restrict__ sMN, float* __restrict__ sPW){
  const float Rg = rc[0]*10.f+1.f, Ri = rc[1]*10.f+1.f, Re = rc[2]*10.f+1.f, Rw = rc[3]*10.f+1.f;
  const float Cai = rc[4]*1e6f+1e5f, Cwe = rc[5]*1e6f+1e5f, Cwi = rc[6]*1e6f+1e5f;
  double Md[9];
  Md[0] = 1.0 + DTSTEP*(-(1.0/Rg + 1.0/Ri)/Cai);
  Md[1] = 0.0;
  Md[2] = DTSTEP*(1.0/((double)Ri*(double)Cai));
  Md[3] = 0.0;
  Md[4] = 1.0 + DTSTEP*(-(1.0/Re + 1.0/Rw)/Cwe);
  Md[5] = DTSTEP*(1.0/((double)Rw*(double)Cwe));
  Md[6] = DTSTEP*(1.0/((double)Ri*(double)Cwi));
  Md[7] = DTSTEP*(1.0/((double)Rw*(double)Cwi));
  Md[8] = 1.0 + DTSTEP*(-(1.0/Rw + 1.0/Ri)/Cwi);
  sMN[0]=(float)Md[0]; sMN[1]=(float)Md[2]; sMN[2]=(float)Md[4]; sMN[3]=(float)Md[5];
  sMN[4]=(float)Md[6]; sMN[5]=(float)Md[7]; sMN[6]=(float)Md[8];
  sMN[7] =(float)(DTSTEP*(1.0/((double)Rg*(double)Cai)));   // N0
  sMN[8] =(float)(DTSTEP*(1.0/(double)Cai));                // N1
  sMN[9] =(float)(DTSTEP*(1.0/(double)Cai));                // N2
  sMN[10]=(float)(DTSTEP*(1.0/((double)Re*(double)Cwe)));   // N5
  sMN[11]=(float)(DTSTEP*(1.0/(double)Cwe));                // N8
  sMN[12]=(float)(DTSTEP*(1.0/(double)Cwi));                // N14
  double C[9];
#pragma unroll
  for (int k=0;k<9;k++) C[k]=Md[k];
  for (int k=1;k<=19;k++){
    matsq3(C);                                   // C = M^(2^k)
    if (k>=3){
#pragma unroll
      for (int j=0;j<9;j++) sPW[(k-3)*9+j] = (float)C[j];
    }
  }
}

struct MN { float M0,M2,M4,M5,M6,M7,M8, N0,N1,N2,N5,N8,N14; };

__device__ inline MN mn_from_lds(const float* __restrict__ sMN){
  MN p;
  p.M0=sMN[0]; p.M2=sMN[1]; p.M4=sMN[2]; p.M5=sMN[3];
  p.M6=sMN[4]; p.M7=sMN[5]; p.M8=sMN[6];
  p.N0=sMN[7]; p.N1=sMN[8]; p.N2=sMN[9];
  p.N5=sMN[10]; p.N8=sMN[11]; p.N14=sMN[12];
  return p;
}

// v = sum_j M^(LCH-1-j) * (N u_j)   via   v <- M v + N u_j
__device__ inline void chunk_v(const float* uu, const MN& mn, float& v0, float& v1, float& v2){
  v0=0.f; v1=0.f; v2=0.f;
#pragma unroll
  for (int j=0;j<LCH;j++){
    const float u0=uu[j*5+0],u1=uu[j*5+1],u2=uu[j*5+2],u3=uu[j*5+3],u4v=uu[j*5+4];
    const float c0 = fmaf(mn.N0,u0, fmaf(mn.N1,u1, mn.N2*u2));
    const float c1 = fmaf(mn.N5,u0, mn.N8*u3);
    const float c2 = mn.N14*u4v;
    const float n0 = fmaf(mn.M0,v0, fmaf(mn.M2,v2, c0));
    const float n1 = fmaf(mn.M4,v1, fmaf(mn.M5,v2, c1));
    const float n2 = fmaf(mn.M6,v0, fmaf(mn.M7,v1, fmaf(mn.M8,v2, c2)));
    v0=n0; v1=n1; v2=n2;
  }
}

// K1: per-chunk v, 512-wide LDS affine scan -> block aggregate ws[blk]
__global__ __launch_bounds__(TPB) void k_agg(const float* __restrict__ u,
                                             const float* __restrict__ rc,
                                             float* __restrict__ ws){
  __shared__ float sMN[13];
  __shared__ float sPW[17*9];
  __shared__ float buf[2][TPB*3];
  const int tid = threadIdx.x;
  const int blk = blockIdx.x;
  const int i   = blk*TPB + tid;                 // chunk id
  float uu[LCH*5];
  const float4* u4 = reinterpret_cast<const float4*>(u) + (size_t)i*(LCH*5/4);
#pragma unroll
  for (int k=0;k<LCH*5/4;k++){
    const float4 q = u4[k];
    uu[k*4+0]=q.x; uu[k*4+1]=q.y; uu[k*4+2]=q.z; uu[k*4+3]=q.w;
  }
  if (tid==0) setup_from_rc(rc, sMN, sPW);
  __syncthreads();
  const MN mn = mn_from_lds(sMN);
  float t0,t1,t2;
  chunk_v(uu, mn, t0,t1,t2);
  buf[0][tid*3+0]=t0; buf[0][tid*3+1]=t1; buf[0][tid*3+2]=t2;
  __syncthreads();
  int cur=0;
#pragma unroll
  for (int r=0;r<9;r++){
    const int d = 1<<r;
    const float Q0=sPW[r*9+0],Q1=sPW[r*9+1],Q2=sPW[r*9+2],
                Q3=sPW[r*9+3],Q4=sPW[r*9+4],Q5=sPW[r*9+5],
                Q6=sPW[r*9+6],Q7=sPW[r*9+7],Q8=sPW[r*9+8];
    float p0=0.f,p1=0.f,p2=0.f;
    if (tid >= d){
      const int s=(tid-d)*3;
      p0=buf[cur][s+0]; p1=buf[cur][s+1]; p2=buf[cur][s+2];
    }
    t0 = fmaf(Q0,p0, fmaf(Q1,p1, fmaf(Q2,p2, t0)));
    t1 = fmaf(Q3,p0, fmaf(Q4,p1, fmaf(Q5,p2, t1)));
    t2 = fmaf(Q6,p0, fmaf(Q7,p1, fmaf(Q8,p2, t2)));
    buf[cur^1][tid*3+0]=t0; buf[cur^1][tid*3+1]=t1; buf[cur^1][tid*3+2]=t2;
    __syncthreads();
    cur ^= 1;
  }
  if (tid==TPB-1){
    ws[blk*3+0]=t0; ws[blk*3+1]=t1; ws[blk*3+2]=t2;
  }
}

// K2: redundant per-block scan of the 256 aggregates -> block start; recompute chunk_v;
// 512-wide scan -> exact chunk starts; replay 8 steps; f32 float4 outputs.
__global__ __launch_bounds__(TPB) void k_expand(const float* __restrict__ u,
                                                const float* __restrict__ rc,
                                                const float* __restrict__ x_init,
                                                const float* __restrict__ ws,
                                                float* __restrict__ out){
  __shared__ float sMN[13];
  __shared__ float sPW[17*9];
  __shared__ float abuf[2][NAGG*3];
  __shared__ float buf[2][TPB*3];
  const int tid = threadIdx.x;
  const int blk = blockIdx.x;
  const int i   = blk*TPB + tid;                 // chunk id
  float uu[LCH*5];
  const float4* u4 = reinterpret_cast<const float4*>(u) + (size_t)i*(LCH*5/4);
#pragma unroll
  for (int k=0;k<LCH*5/4;k++){
    const float4 q = u4[k];
    uu[k*4+0]=q.x; uu[k*4+1]=q.y; uu[k*4+2]=q.z; uu[k*4+3]=q.w;
  }
  if (tid==0) setup_from_rc(rc, sMN, sPW);
  __syncthreads();
  const float xi0=x_init[0], xi1=x_init[1], xi2=x_init[2];
  // ---- redundant aggregate scan over 256 block aggregates (threads 0..255) ----
  float a0=0.f,a1=0.f,a2=0.f;
  if (tid < NAGG){
    a0=ws[tid*3+0]; a1=ws[tid*3+1]; a2=ws[tid*3+2];
    if (tid==0){                                 // fold x_init: state after block 0
      const float R0=sPW[9*9+0],R1=sPW[9*9+1],R2=sPW[9*9+2],
                  R3=sPW[9*9+3],R4=sPW[9*9+4],R5=sPW[9*9+5],
                  R6=sPW[9*9+6],R7=sPW[9*9+7],R8=sPW[9*9+8];
      a0 = fmaf(R0,xi0, fmaf(R1,xi1, fmaf(R2,xi2, a0)));
      a1 = fmaf(R3,xi0, fmaf(R4,xi1, fmaf(R5,xi2, a1)));
      a2 = fmaf(R6,xi0, fmaf(R7,xi1, fmaf(R8,xi2, a2)));
    }
    abuf[0][tid*3+0]=a0; abuf[0][tid*3+1]=a1; abuf[0][tid*3+2]=a2;
  }
  __syncthreads();
  int cur=0;
#pragma unroll
  for (int r=0;r<8;r++){
    const int d = 1<<r;
    const float Q0=sPW[(9+r)*9+0],Q1=sPW[(9+r)*9+1],Q2=sPW[(9+r)*9+2],
                Q3=sPW[(9+r)*9+3],Q4=sPW[(9+r)*9+4],Q5=sPW[(9+r)*9+5],
                Q6=sPW[(9+r)*9+6],Q7=sPW[(9+r)*9+7],Q8=sPW[(9+r)*9+8];
    float p0=0.f,p1=0.f,p2=0.f;
    if (tid < NAGG && tid >= d){
      const int s=(tid-d)*3;
      p0=abuf[cur][s+0]; p1=abuf[cur][s+1]; p2=abuf[cur][s+2];
    }
    if (tid < NAGG){
      a0 = fmaf(Q0,p0, fmaf(Q1,p1, fmaf(Q2,p2, a0)));
      a1 = fmaf(Q3,p0, fmaf(Q4,p1, fmaf(Q5,p2, a1)));
      a2 = fmaf(Q6,p0, fmaf(Q7,p1, fmaf(Q8,p2, a2)));
      abuf[cur^1][tid*3+0]=a0; abuf[cur^1][tid*3+1]=a1; abuf[cur^1][tid*3+2]=a2;
    }
    __syncthreads();
    cur ^= 1;
  }
  // block start state
  float S0,S1,S2;
  if (blk==0){ S0=xi0; S1=xi1; S2=xi2; }
  else { const int s=(blk-1)*3; S0=abuf[cur][s+0]; S1=abuf[cur][s+1]; S2=abuf[cur][s+2]; }
  // ---- intra-block: chunk_v, fold S into chunk 0, 512-wide scan ----
  const MN mn = mn_from_lds(sMN);
  float t0,t1,t2;
  chunk_v(uu, mn, t0,t1,t2);
  if (tid==0){
    const float P0=sPW[0],P1=sPW[1],P2=sPW[2],
                P3=sPW[3],P4=sPW[4],P5=sPW[5],
                P6=sPW[6],P7=sPW[7],P8=sPW[8];
    const float b0 = fmaf(P0,S0, fmaf(P1,S1, fmaf(P2,S2, t0)));
    const float b1 = fmaf(P3,S0, fmaf(P4,S1, fmaf(P5,S2, t1)));
    const float b2 = fmaf(P6,S0, fmaf(P7,S1, fmaf(P8,S2, t2)));
    t0=b0; t1=b1; t2=b2;
  }
  buf[0][tid*3+0]=t0; buf[0][tid*3+1]=t1; buf[0][tid*3+2]=t2;
  __syncthreads();
  cur=0;
#pragma unroll
  for (int r=0;r<9;r++){
    const int d = 1<<r;
    const float Q0=sPW[r*9+0],Q1=sPW[r*9+1],Q2=sPW[r*9+2],
                Q3=sPW[r*9+3],Q4=sPW[r*9+4],Q5=sPW[r*9+5],
                Q6=sPW[r*9+6],Q7=sPW[r*9+7],Q8=sPW[r*9+8];
    float p0=0.f,p1=0.f,p2=0.f;
    if (tid >= d){
      const int s=(tid-d)*3;
      p0=buf[cur][s+0]; p1=buf[cur][s+1]; p2=buf[cur][s+2];
    }
    t0 = fmaf(Q0,p0, fmaf(Q1,p1, fmaf(Q2,p2, t0)));
    t1 = fmaf(Q3,p0, fmaf(Q4,p1, fmaf(Q5,p2, t1)));
    t2 = fmaf(Q6,p0, fmaf(Q7,p1, fmaf(Q8,p2, t2)));
    buf[cur^1][tid*3+0]=t0; buf[cur^1][tid*3+1]=t1; buf[cur^1][tid*3+2]=t2;
    __syncthreads();
    cur ^= 1;
  }
  // chunk start = previous thread's inclusive value; tid 0 -> S
  float x0,x1,x2;
  if (tid==0){ x0=S0; x1=S1; x2=S2; }
  else { const int s=(tid-1)*3; x0=buf[cur][s+0]; x1=buf[cur][s+1]; x2=buf[cur][s+2]; }
  // ---- replay 8 steps, write f32 outputs ----
  float px[LCH*3], py[LCH];
#pragma unroll
  for (int j=0;j<LCH;j++){
    py[j]=x0;                                    // y_t = C x_t (pre-update)
    const float u0=uu[j*5+0],u1=uu[j*5+1],u2=uu[j*5+2],u3=uu[j*5+3],u4v=uu[j*5+4];
    const float c0 = fmaf(mn.N0,u0, fmaf(mn.N1,u1, mn.N2*u2));
    const float c1 = fmaf(mn.N5,u0, mn.N8*u3);
    const float c2 = mn.N14*u4v;
    const float n0 = fmaf(mn.M0,x0, fmaf(mn.M2,x2, c0));
    const float n1 = fmaf(mn.M4,x1, fmaf(mn.M5,x2, c1));
    const float n2 = fmaf(mn.M6,x0, fmaf(mn.M7,x1, fmaf(mn.M8,x2, c2)));
    x0=n0; x1=n1; x2=n2;
    px[j*3+0]=x0; px[j*3+1]=x1; px[j*3+2]=x2;    // xsol_t = x_{t+1}
  }
  float4* xo4 = reinterpret_cast<float4*>(out) + (size_t)i*6;
#pragma unroll
  for (int m=0;m<6;m++)
    xo4[m] = make_float4(px[4*m+0],px[4*m+1],px[4*m+2],px[4*m+3]);
  float4* yo4 = reinterpret_cast<float4*>(out) + (size_t)(3*T_STEPS/4) + (size_t)i*2;
  yo4[0] = make_float4(py[0],py[1],py[2],py[3]);
  yo4[1] = make_float4(py[4],py[5],py[6],py[7]);
}

extern "C" void kernel_launch(void* const* d_in, const int* in_sizes, int n_in,
                              void* d_out, int out_size, void* d_ws, size_t ws_size,
                              hipStream_t stream) {
  (void)out_size; (void)ws_size;
  const float* x_init = (const float*)d_in[0];
  const float* u      = (const float*)d_in[1];
  const float* rc     = (const float*)d_in[2];
  for (int k=0;k<n_in;k++){
    if (in_sizes[k]==3) x_init = (const float*)d_in[k];
    else if (in_sizes[k]==7) rc = (const float*)d_in[k];
    else if (in_sizes[k]==T_STEPS*5) u = (const float*)d_in[k];
  }
  float* ws  = (float*)d_ws;                // 256 aggregates × 3 floats = 3 KB
  float* out = (float*)d_out;               // f32 outputs

  k_agg   <<<NBLK, TPB, 0, stream>>>(u, rc, ws);
  k_expand<<<NBLK, TPB, 0, stream>>>(u, rc, x_init, ws, out);
}